// Round 11
// baseline (4251.328 us; speedup 1.0000x reference)
//
#include <hip/hip_runtime.h>
#include <hip/hip_fp16.h>

#define B_  64
#define T_  2048
#define I_  64
#define H_  256
#define G4_ 1024   // 4*H

typedef _Float16 f16x8 __attribute__((ext_vector_type(8)));
typedef float    f32x4 __attribute__((ext_vector_type(4)));

__device__ __forceinline__ ushort f2h(float v) {
    return __builtin_bit_cast(ushort, (_Float16)v);
}
__device__ __forceinline__ float h2f(ushort v) {
    return (float)__builtin_bit_cast(_Float16, v);
}

// ---------------------------------------------------------------------------
// Repack W_hh fp32 [1024][256] -> f16 MFMA A-fragments
//   af[tile=64][kc=8][lane=64][j2=8]
// 16x16x32 A layout: lane l holds A[row = l&15][k = (l>>4)*8 + j2]
// (verified correct end-to-end in round 10).
// ---------------------------------------------------------------------------
__global__ void repack_kernel(const float* __restrict__ Whh, ushort* __restrict__ af) {
    int o  = blockIdx.x * 256 + threadIdx.x;   // 0 .. 262143 (f16 elements)
    int j2 = o & 7;
    int l  = (o >> 3) & 63;
    int kc = (o >> 9) & 7;
    int tj = o >> 12;
    int row = tj * 16 + (l & 15);
    int col = kc * 32 + (l >> 4) * 8 + j2;
    af[o] = f2h(Whh[row * 256 + col]);
}

// ---------------------------------------------------------------------------
// gx2 = x @ W_ih^T + b_ih + b_hh, TRANSPOSED f16 layout [bt][hd][gate] so the
// lstm kernel fetches one ushort4 per (t,hd).  grid = ((64*TCc)/32, 4).
// ---------------------------------------------------------------------------
__global__ __launch_bounds__(256) void gx_kernel(
    const float* __restrict__ x, const float* __restrict__ Wih,
    const float* __restrict__ bih, const float* __restrict__ bhh,
    ushort* __restrict__ gx2, int t0, int TCc) {

    __shared__ float xs[32][64];
    const int bt0 = blockIdx.x * 32;
    const int gq  = blockIdx.y;                 // gate 0..3 (i,f,g,o)
    const int row = gq * 256 + threadIdx.x;     // W_ih row

    for (int i = threadIdx.x; i < 512; i += 256) {
        int r  = i >> 4, c4 = i & 15;
        int bt = bt0 + r;
        int b  = bt / TCc;
        int tl = bt - b * TCc;
        *(float4*)(&xs[r][c4 * 4]) =
            *(const float4*)(&x[(((size_t)b * T_) + t0 + tl) * I_ + c4 * 4]);
    }
    __syncthreads();

    float w[64];
#pragma unroll
    for (int k = 0; k < 64; ++k) w[k] = Wih[row * I_ + k];
    const float bias = bih[row] + bhh[row];

    for (int i = 0; i < 32; ++i) {
        float acc = bias;
#pragma unroll
        for (int k4 = 0; k4 < 16; ++k4) {
            float4 xq = *(const float4*)(&xs[i][k4 * 4]);
            acc = fmaf(w[k4 * 4 + 0], xq.x, acc);
            acc = fmaf(w[k4 * 4 + 1], xq.y, acc);
            acc = fmaf(w[k4 * 4 + 2], xq.z, acc);
            acc = fmaf(w[k4 * 4 + 3], xq.w, acc);
        }
        gx2[((size_t)(bt0 + i) * 256 + threadIdx.x) * 4 + gq] = f2h(acc);
    }
}

// ---------------------------------------------------------------------------
// Persistent per-batch LSTM, full-MFMA matvec, round-11 SCHEDULE FIX.
// r10 diagnosis: 4300 cyc/step, of which ~3400 stall -- the exec-masked
// B-read (4/64 lanes) fed 4 dependent MFMAs with nothing in flight.
// Fixes: (1) B-read unmasked: lanes l&15!=0 load broadcast garbage whose
// products land in C columns 1..15 which are never read -- no divergence.
// (2) kc-outer loop, depth-1 B prefetch: next B-frag issued before current
// MFMAs.  (3) streamed A-frags early-issued one kc ahead (static unroll).
// Budget: 192 A(acc) + 16 C + ~40 working ~= 248 <= 256/wave -- no spill.
// ---------------------------------------------------------------------------
__global__ __launch_bounds__(512, 1)
void lstm_kernel(
    const ushort* __restrict__ af, const ushort* __restrict__ gx2,
    ushort* __restrict__ hbuf,     // [B][TCc][H] f16
    float* __restrict__ state,     // [2][64][256]: c then h
    int TCc, int first) {

    __shared__ __align__(16) ushort sfrag[8 * 16 * 64 * 8]; // streamed frags, 128 KB
    __shared__ __align__(16) ushort hs[2][256];             // h dbuf (f16)
    __shared__ __align__(16) float  gbuf[4][256];           // gate partials, 4 KB

    const int tid = threadIdx.x;
    const int l   = tid & 63;
    const int w   = tid >> 6;
    const int hd  = tid & 255;
    const int b   = blockIdx.x;
    const bool q0 = (w < 4);

    // --- resident A-frags: kc 0..5 of this wave's 8 tiles (48 x b128) ---
    f16x8 wres[8][6];
#pragma unroll
    for (int j = 0; j < 8; ++j)
#pragma unroll
        for (int kc = 0; kc < 6; ++kc) {
            uint4 v = *(const uint4*)(af + (size_t)(((w * 8 + j) * 8 + kc) * 64 + l) * 8);
            wres[j][kc] = __builtin_bit_cast(f16x8, v);
        }
    // --- streamed A-frags: kc 6,7 -> static LDS (16 x b128 per wave) ---
#pragma unroll
    for (int j = 0; j < 8; ++j)
#pragma unroll
        for (int kc = 6; kc < 8; ++kc) {
            uint4 v = *(const uint4*)(af + (size_t)(((w * 8 + j) * 8 + kc) * 64 + l) * 8);
            *(uint4*)(sfrag + (size_t)((w * 16 + j * 2 + (kc - 6)) * 64 + l) * 8) = v;
        }
    // per-wave base for streamed-frag reads: + (j*2 + s)*512 f16 (static offs)
    const ushort* sbase = sfrag + (size_t)(w * 16 * 64 + l) * 8;

    float c = 0.f, h = 0.f;
    if (q0) {
        if (!first) {
            c = state[b * H_ + hd];
            h = state[B_ * H_ + b * H_ + hd];
        }
        hs[0][hd] = f2h(h);
    }
    __syncthreads();

    const ushort* gxb = gx2 + (size_t)b * TCc * G4_;
    ushort* hb = hbuf + (size_t)b * TCc * H_;

    ushort4 cg = make_ushort4(0, 0, 0, 0);
    if (q0) cg = *(const ushort4*)(gxb + hd * 4);

    const int bofs = (l >> 4) * 8;   // B-frag per-lane offset within a kc row

    for (int tl = 0; tl < TCc; ++tl) {
        ushort4 ng = cg;
        if (q0) {
            const int tn = (tl + 1 < TCc) ? tl + 1 : tl;
            ng = *(const ushort4*)(gxb + (size_t)tn * G4_ + hd * 4);
        }
        const ushort* hsr = hs[tl & 1];

        // ---------------- phase 1: MFMA over 8 tiles (2 groups of 4) --------
#pragma unroll
        for (int grp = 0; grp < 2; ++grp) {
            const int j0 = grp * 4;
            f32x4 C0 = {0.f, 0.f, 0.f, 0.f};
            f32x4 C1 = {0.f, 0.f, 0.f, 0.f};
            f32x4 C2 = {0.f, 0.f, 0.f, 0.f};
            f32x4 C3 = {0.f, 0.f, 0.f, 0.f};

            // depth-1 pipelined B; streamed A issued one kc early
            uint4 Bcur = *(const uint4*)(hsr + bofs);            // kc = 0
            uint4 A60, A61, A62, A63, A70, A71, A72, A73;
#pragma unroll
            for (int kc = 0; kc < 8; ++kc) {
                uint4 Bnxt = Bcur;
                if (kc < 7)
                    Bnxt = *(const uint4*)(hsr + (kc + 1) * 32 + bofs);
                if (kc == 5) {   // issue kc-6 streamed frags early
                    A60 = *(const uint4*)(sbase + ((j0 + 0) * 2 + 0) * 512);
                    A61 = *(const uint4*)(sbase + ((j0 + 1) * 2 + 0) * 512);
                    A62 = *(const uint4*)(sbase + ((j0 + 2) * 2 + 0) * 512);
                    A63 = *(const uint4*)(sbase + ((j0 + 3) * 2 + 0) * 512);
                }
                if (kc == 6) {   // issue kc-7 streamed frags early
                    A70 = *(const uint4*)(sbase + ((j0 + 0) * 2 + 1) * 512);
                    A71 = *(const uint4*)(sbase + ((j0 + 1) * 2 + 1) * 512);
                    A72 = *(const uint4*)(sbase + ((j0 + 2) * 2 + 1) * 512);
                    A73 = *(const uint4*)(sbase + ((j0 + 3) * 2 + 1) * 512);
                }
                f16x8 Bf = __builtin_bit_cast(f16x8, Bcur);
                if (kc < 6) {
                    C0 = __builtin_amdgcn_mfma_f32_16x16x32_f16(wres[j0 + 0][kc], Bf, C0, 0, 0, 0);
                    C1 = __builtin_amdgcn_mfma_f32_16x16x32_f16(wres[j0 + 1][kc], Bf, C1, 0, 0, 0);
                    C2 = __builtin_amdgcn_mfma_f32_16x16x32_f16(wres[j0 + 2][kc], Bf, C2, 0, 0, 0);
                    C3 = __builtin_amdgcn_mfma_f32_16x16x32_f16(wres[j0 + 3][kc], Bf, C3, 0, 0, 0);
                } else if (kc == 6) {
                    C0 = __builtin_amdgcn_mfma_f32_16x16x32_f16(__builtin_bit_cast(f16x8, A60), Bf, C0, 0, 0, 0);
                    C1 = __builtin_amdgcn_mfma_f32_16x16x32_f16(__builtin_bit_cast(f16x8, A61), Bf, C1, 0, 0, 0);
                    C2 = __builtin_amdgcn_mfma_f32_16x16x32_f16(__builtin_bit_cast(f16x8, A62), Bf, C2, 0, 0, 0);
                    C3 = __builtin_amdgcn_mfma_f32_16x16x32_f16(__builtin_bit_cast(f16x8, A63), Bf, C3, 0, 0, 0);
                } else {
                    C0 = __builtin_amdgcn_mfma_f32_16x16x32_f16(__builtin_bit_cast(f16x8, A70), Bf, C0, 0, 0, 0);
                    C1 = __builtin_amdgcn_mfma_f32_16x16x32_f16(__builtin_bit_cast(f16x8, A71), Bf, C1, 0, 0, 0);
                    C2 = __builtin_amdgcn_mfma_f32_16x16x32_f16(__builtin_bit_cast(f16x8, A72), Bf, C2, 0, 0, 0);
                    C3 = __builtin_amdgcn_mfma_f32_16x16x32_f16(__builtin_bit_cast(f16x8, A73), Bf, C3, 0, 0, 0);
                }
                Bcur = Bnxt;
            }
            // C col 0 -> gbuf: lane l&15==0 holds rows lr..lr+3 in 4 regs
            if ((l & 15) == 0) {
                const int lr  = (l >> 4) * 4;
                const int tj0 = w * 8 + j0;
                *(f32x4*)(&gbuf[(tj0 + 0) >> 4][((tj0 + 0) & 15) * 16 + lr]) = C0;
                *(f32x4*)(&gbuf[(tj0 + 1) >> 4][((tj0 + 1) & 15) * 16 + lr]) = C1;
                *(f32x4*)(&gbuf[(tj0 + 2) >> 4][((tj0 + 2) & 15) * 16 + lr]) = C2;
                *(f32x4*)(&gbuf[(tj0 + 3) >> 4][((tj0 + 3) & 15) * 16 + lr]) = C3;
            }
        }
        __syncthreads();

        // ---------------- phase 2: elementwise (waves 0-3) ------------------
        if (q0) {
            float ai  = gbuf[0][hd] + h2f(cg.x);
            float afv = gbuf[1][hd] + h2f(cg.y);
            float ag  = gbuf[2][hd] + h2f(cg.z);
            float ao  = gbuf[3][hd] + h2f(cg.w);

            float si = __builtin_amdgcn_rcpf(1.f + __expf(-ai));
            float sf = __builtin_amdgcn_rcpf(1.f + __expf(-afv));
            float so = __builtin_amdgcn_rcpf(1.f + __expf(-ao));
            float eg = __expf(2.f * ag);
            float tg = (eg - 1.f) * __builtin_amdgcn_rcpf(eg + 1.f);
            c = sf * c + si * tg;
            float ec = __expf(2.f * c);
            float tc = (ec - 1.f) * __builtin_amdgcn_rcpf(ec + 1.f);
            h = so * tc;

            ushort hh = f2h(h);
            hs[(tl + 1) & 1][hd] = hh;
            hb[(size_t)tl * H_ + hd] = hh;
            cg = ng;
        }
        __syncthreads();
    }

    if (q0) {
        state[b * H_ + hd]           = c;
        state[B_ * H_ + b * H_ + hd] = h;
    }
}

// ---------------------------------------------------------------------------
// out[b,t] = sum_hd h[b,t,hd] * Wo[hd] + bo.  h f16 rows, fully dense reads.
// ---------------------------------------------------------------------------
__global__ __launch_bounds__(256) void proj_kernel(
    const ushort* __restrict__ hbuf, const float* __restrict__ Wo,
    const float* __restrict__ bo, float* __restrict__ out, int t0, int TCc) {

    const int lane = threadIdx.x & 63;
    const int wid  = blockIdx.x * 4 + (threadIdx.x >> 6);
    const int nw   = gridDim.x * 4;
    const int rows = B_ * TCc;

    float4 w = *(const float4*)(Wo + lane * 4);
    const float bov = bo[0];

    for (int r = wid; r < rows; r += nw) {
        const ushort* hp = hbuf + (size_t)r * H_ + lane * 4;
        ushort4 u = *(const ushort4*)hp;
        float p = h2f(u.x) * w.x + h2f(u.y) * w.y + h2f(u.z) * w.z + h2f(u.w) * w.w;
#pragma unroll
        for (int m = 1; m < 64; m <<= 1) p += __shfl_xor(p, m, 64);
        if (lane == 0) {
            int b  = r / TCc;
            int tl = r - b * TCc;
            out[(size_t)b * T_ + t0 + tl] = p + bov;
        }
    }
}

// ---------------------------------------------------------------------------
extern "C" void kernel_launch(void* const* d_in, const int* in_sizes, int n_in,
                              void* d_out, int out_size, void* d_ws, size_t ws_size,
                              hipStream_t stream) {
    const float* x   = (const float*)d_in[0];
    const float* Wih = (const float*)d_in[1];
    const float* Whh = (const float*)d_in[2];
    const float* bih = (const float*)d_in[3];
    const float* bhh = (const float*)d_in[4];
    const float* Wo  = (const float*)d_in[5];
    const float* bo  = (const float*)d_in[6];
    float* out = (float*)d_out;

    char* ws = (char*)d_ws;
    ushort* af    = (ushort*)ws;                              // 512 KB A-frags
    float*  state = (float*)(ws + 512 * 1024);                // 128 KB
    char*   dyn   = ws + 640 * 1024;                          // gx2 + hbuf chunks

    size_t avail = (ws_size > 640 * 1024) ? ws_size - 640 * 1024 : 0;
    // per (b,t): gx2 row 2048 B + hbuf row 512 B
    long long tcmax = (long long)(avail / ((size_t)B_ * (G4_ + H_) * 2));
    // Cap chunks at 512 steps so gx2 (64MB) + hbuf (16MB) stay L3-resident.
    int TC = (tcmax > 512) ? 512 : (int)tcmax;
    TC &= ~63;               // multiple of 64
    if (TC < 64) TC = 64;    // minimum viable chunk

    repack_kernel<<<1024, 256, 0, stream>>>(Whh, af);

    for (int t0 = 0; t0 < T_; t0 += TC) {
        int TCc = (T_ - t0 < TC) ? (T_ - t0) : TC;
        ushort* gxb  = (ushort*)dyn;
        ushort* hbuf = (ushort*)(dyn + (size_t)B_ * TCc * G4_ * 2);
        dim3 g1((B_ * TCc) / 32, 4);
        gx_kernel<<<g1, 256, 0, stream>>>(x, Wih, bih, bhh, gxb, t0, TCc);
        lstm_kernel<<<B_, 512, 0, stream>>>(af, gxb, hbuf, state, TCc, t0 == 0 ? 1 : 0);
        proj_kernel<<<256, 256, 0, stream>>>(hbuf, Wo, bo, out, t0, TCc);
    }
    (void)in_sizes; (void)n_in; (void)out_size;
}

// Round 12
// 3944.402 us; speedup vs baseline: 1.0778x; 1.0778x over previous
//
#include <hip/hip_runtime.h>
#include <hip/hip_fp16.h>

#define B_  64
#define T_  2048
#define I_  64
#define H_  256
#define G4_ 1024   // 4*H

typedef _Float16 f16x8 __attribute__((ext_vector_type(8)));
typedef float    f32x4 __attribute__((ext_vector_type(4)));

__device__ __forceinline__ ushort f2h(float v) {
    return __builtin_bit_cast(ushort, (_Float16)v);
}
__device__ __forceinline__ float h2f(ushort v) {
    return (float)__builtin_bit_cast(_Float16, v);
}

// ---------------------------------------------------------------------------
// Repack W_hh fp32 [1024][256] -> f16 MFMA A-fragments
//   af[tile=64][kc=8][lane=64][j2=8]
// 16x16x32 A layout: lane l holds A[row = l&15][k = (l>>4)*8 + j2]
// (verified correct end-to-end in rounds 10-11).
// ---------------------------------------------------------------------------
__global__ void repack_kernel(const float* __restrict__ Whh, ushort* __restrict__ af) {
    int o  = blockIdx.x * 256 + threadIdx.x;   // 0 .. 262143 (f16 elements)
    int j2 = o & 7;
    int l  = (o >> 3) & 63;
    int kc = (o >> 9) & 7;
    int tj = o >> 12;
    int row = tj * 16 + (l & 15);
    int col = kc * 32 + (l >> 4) * 8 + j2;
    af[o] = f2h(Whh[row * 256 + col]);
}

// ---------------------------------------------------------------------------
// gx2 = x @ W_ih^T + b_ih + b_hh, TRANSPOSED f16 layout [bt][hd][gate] so the
// lstm kernel fetches one ushort4 per (t,hd).  grid = ((64*TCc)/32, 4).
// ---------------------------------------------------------------------------
__global__ __launch_bounds__(256) void gx_kernel(
    const float* __restrict__ x, const float* __restrict__ Wih,
    const float* __restrict__ bih, const float* __restrict__ bhh,
    ushort* __restrict__ gx2, int t0, int TCc) {

    __shared__ float xs[32][64];
    const int bt0 = blockIdx.x * 32;
    const int gq  = blockIdx.y;                 // gate 0..3 (i,f,g,o)
    const int row = gq * 256 + threadIdx.x;     // W_ih row

    for (int i = threadIdx.x; i < 512; i += 256) {
        int r  = i >> 4, c4 = i & 15;
        int bt = bt0 + r;
        int b  = bt / TCc;
        int tl = bt - b * TCc;
        *(float4*)(&xs[r][c4 * 4]) =
            *(const float4*)(&x[(((size_t)b * T_) + t0 + tl) * I_ + c4 * 4]);
    }
    __syncthreads();

    float w[64];
#pragma unroll
    for (int k = 0; k < 64; ++k) w[k] = Wih[row * I_ + k];
    const float bias = bih[row] + bhh[row];

    for (int i = 0; i < 32; ++i) {
        float acc = bias;
#pragma unroll
        for (int k4 = 0; k4 < 16; ++k4) {
            float4 xq = *(const float4*)(&xs[i][k4 * 4]);
            acc = fmaf(w[k4 * 4 + 0], xq.x, acc);
            acc = fmaf(w[k4 * 4 + 1], xq.y, acc);
            acc = fmaf(w[k4 * 4 + 2], xq.z, acc);
            acc = fmaf(w[k4 * 4 + 3], xq.w, acc);
        }
        gx2[((size_t)(bt0 + i) * 256 + threadIdx.x) * 4 + gq] = f2h(acc);
    }
}

// ---------------------------------------------------------------------------
// Persistent per-batch LSTM, full-MFMA matvec, round-12 STREAM REBALANCE.
// r11 diagnosis: ~270 KB/step through the ~128B/cyc LDS pipe (B re-read per
// group + 16 streamed frags) = 2100+ cyc -- pipe-volume-bound.
// Changes: (1) B read ONCE per step (8 reads, no group split; all 8 C tiles
// accumulate simultaneously).  (2) A-frag 3-way split: kc0-3 resident in acc
// (128 dw, MFMA-native), kc4-5 from static LDS (128 KB), kc6-7 from GLOBAL
// af -- L2-hot (512 KB shared by 8 blocks/XCD), vmem pipe runs parallel to
// LDS pipe and MFMA.  (3) loads staged in halves to keep arch live <= ~125
// (arch cap 128 with acc full; overflow would hit scratch -- r9/r11 lesson).
// ---------------------------------------------------------------------------
__global__ __launch_bounds__(512, 1)
void lstm_kernel(
    const ushort* __restrict__ af, const ushort* __restrict__ gx2,
    ushort* __restrict__ hbuf,     // [B][TCc][H] f16
    float* __restrict__ state,     // [2][64][256]: c then h
    int TCc, int first) {

    __shared__ __align__(16) ushort sfrag[8 * 8 * 2 * 512]; // kc4,5 frags, 128 KB
    __shared__ __align__(16) ushort hs[2][256];             // h dbuf (f16)
    __shared__ __align__(16) float  gbuf[4][256];           // gate partials, 4 KB

    const int tid = threadIdx.x;
    const int l   = tid & 63;
    const int w   = tid >> 6;
    const int u   = l >> 4;
    const int hd  = tid & 255;
    const int b   = blockIdx.x;
    const bool q0 = (w < 4);

    // --- resident A-frags: kc 0..3 of this wave's 8 tiles (32 x b128, acc) ---
    f16x8 wres[8][4];
#pragma unroll
    for (int j = 0; j < 8; ++j)
#pragma unroll
        for (int kc = 0; kc < 4; ++kc) {
            uint4 v = *(const uint4*)(af + (size_t)(((w * 8 + j) * 8 + kc) * 64 + l) * 8);
            wres[j][kc] = __builtin_bit_cast(f16x8, v);
        }
    // --- LDS A-frags: kc 4,5 -> sfrag[((w*8+j)*2+s)*512 + l*8] ---
#pragma unroll
    for (int j = 0; j < 8; ++j)
#pragma unroll
        for (int s = 0; s < 2; ++s) {
            uint4 v = *(const uint4*)(af + (size_t)(((w * 8 + j) * 8 + 4 + s) * 64 + l) * 8);
            *(uint4*)(sfrag + ((w * 8 + j) * 2 + s) * 512 + l * 8) = v;
        }
    // global-streamed kc 6,7 base: element off = w*32768 + j*4096 + kc*512 + l*8
    const ushort* awl = af + (size_t)w * 32768 + l * 8;
    // LDS read base for this thread's sfrag slice (imm offsets per j,s)
    const ushort* swl = sfrag + w * 8192 + l * 8;

    float c = 0.f, h = 0.f;
    if (q0) {
        if (!first) {
            c = state[b * H_ + hd];
            h = state[B_ * H_ + b * H_ + hd];
        }
        hs[0][hd] = f2h(h);
    }
    __syncthreads();

    const ushort* gxr = gx2 + (size_t)b * TCc * G4_;
    ushort* hb = hbuf + (size_t)b * TCc * H_;

    for (int tl = 0; tl < TCc; ++tl) {
        const ushort* hsr = hs[tl & 1];
        const int bo = u * 8;               // B-frag per-lane offset

        // gate bias+input term for this step (q0; latency hidden by phase 1)
        ushort4 cg;
        if (q0) cg = *(const ushort4*)(gxr + (size_t)tl * G4_ + hd * 4);

        // ---- issue global kc6 (halves) early; kc7 later ----
        uint4 g6[8], g7[8];
#pragma unroll
        for (int j = 0; j < 4; ++j) g6[j] = *(const uint4*)(awl + j * 4096 + 6 * 512);

        f32x4 C[8];
#pragma unroll
        for (int j = 0; j < 8; ++j) C[j] = (f32x4){0.f, 0.f, 0.f, 0.f};

        uint4 B0 = *(const uint4*)(hsr + 0 * 32 + bo);
        uint4 B1 = *(const uint4*)(hsr + 1 * 32 + bo);

        // kc0 (resident)
#pragma unroll
        for (int j = 0; j < 8; ++j)
            C[j] = __builtin_amdgcn_mfma_f32_16x16x32_f16(wres[j][0], __builtin_bit_cast(f16x8, B0), C[j], 0, 0, 0);
        uint4 B2 = *(const uint4*)(hsr + 2 * 32 + bo);
#pragma unroll
        for (int j = 4; j < 8; ++j) g6[j] = *(const uint4*)(awl + j * 4096 + 6 * 512);

        // kc1
#pragma unroll
        for (int j = 0; j < 8; ++j)
            C[j] = __builtin_amdgcn_mfma_f32_16x16x32_f16(wres[j][1], __builtin_bit_cast(f16x8, B1), C[j], 0, 0, 0);
        uint4 B3 = *(const uint4*)(hsr + 3 * 32 + bo);
        uint4 aA[8];
#pragma unroll
        for (int j = 0; j < 8; ++j) aA[j] = *(const uint4*)(swl + (j * 2 + 0) * 512);  // kc4

        // kc2
#pragma unroll
        for (int j = 0; j < 8; ++j)
            C[j] = __builtin_amdgcn_mfma_f32_16x16x32_f16(wres[j][2], __builtin_bit_cast(f16x8, B2), C[j], 0, 0, 0);
        uint4 B4 = *(const uint4*)(hsr + 4 * 32 + bo);

        // kc3
#pragma unroll
        for (int j = 0; j < 8; ++j)
            C[j] = __builtin_amdgcn_mfma_f32_16x16x32_f16(wres[j][3], __builtin_bit_cast(f16x8, B3), C[j], 0, 0, 0);
        uint4 B5 = *(const uint4*)(hsr + 5 * 32 + bo);
        uint4 aB[8];
#pragma unroll
        for (int j = 0; j < 8; ++j) aB[j] = *(const uint4*)(swl + (j * 2 + 1) * 512);  // kc5

        // kc4 (LDS)
#pragma unroll
        for (int j = 0; j < 8; ++j)
            C[j] = __builtin_amdgcn_mfma_f32_16x16x32_f16(__builtin_bit_cast(f16x8, aA[j]), __builtin_bit_cast(f16x8, B4), C[j], 0, 0, 0);
        uint4 B6 = *(const uint4*)(hsr + 6 * 32 + bo);
#pragma unroll
        for (int j = 0; j < 4; ++j) g7[j] = *(const uint4*)(awl + j * 4096 + 7 * 512);

        // kc5 (LDS)
#pragma unroll
        for (int j = 0; j < 8; ++j)
            C[j] = __builtin_amdgcn_mfma_f32_16x16x32_f16(__builtin_bit_cast(f16x8, aB[j]), __builtin_bit_cast(f16x8, B5), C[j], 0, 0, 0);
        uint4 B7 = *(const uint4*)(hsr + 7 * 32 + bo);
#pragma unroll
        for (int j = 4; j < 8; ++j) g7[j] = *(const uint4*)(awl + j * 4096 + 7 * 512);

        // kc6 (global)
#pragma unroll
        for (int j = 0; j < 8; ++j)
            C[j] = __builtin_amdgcn_mfma_f32_16x16x32_f16(__builtin_bit_cast(f16x8, g6[j]), __builtin_bit_cast(f16x8, B6), C[j], 0, 0, 0);
        // kc7 (global)
#pragma unroll
        for (int j = 0; j < 8; ++j)
            C[j] = __builtin_amdgcn_mfma_f32_16x16x32_f16(__builtin_bit_cast(f16x8, g7[j]), __builtin_bit_cast(f16x8, B7), C[j], 0, 0, 0);

        // C col 0 -> gbuf (lanes l&15==0 hold rows 4u..4u+3 in 4 regs)
        if ((l & 15) == 0) {
            const int lr = u * 4;
#pragma unroll
            for (int j = 0; j < 8; ++j) {
                const int tj = w * 8 + j;
                *(f32x4*)(&gbuf[tj >> 4][(tj & 15) * 16 + lr]) = C[j];
            }
        }
        __syncthreads();

        // ---------------- phase 2: elementwise (waves 0-3) ------------------
        if (q0) {
            float ai  = gbuf[0][hd] + h2f(cg.x);
            float afv = gbuf[1][hd] + h2f(cg.y);
            float ag  = gbuf[2][hd] + h2f(cg.z);
            float ao  = gbuf[3][hd] + h2f(cg.w);

            float si = __builtin_amdgcn_rcpf(1.f + __expf(-ai));
            float sf = __builtin_amdgcn_rcpf(1.f + __expf(-afv));
            float so = __builtin_amdgcn_rcpf(1.f + __expf(-ao));
            float eg = __expf(2.f * ag);
            float tg = (eg - 1.f) * __builtin_amdgcn_rcpf(eg + 1.f);
            c = sf * c + si * tg;
            float ec = __expf(2.f * c);
            float tc = (ec - 1.f) * __builtin_amdgcn_rcpf(ec + 1.f);
            h = so * tc;

            ushort hh = f2h(h);
            hs[(tl + 1) & 1][hd] = hh;
            hb[(size_t)tl * H_ + hd] = hh;
        }
        __syncthreads();
    }

    if (q0) {
        state[b * H_ + hd]           = c;
        state[B_ * H_ + b * H_ + hd] = h;
    }
}

// ---------------------------------------------------------------------------
// out[b,t] = sum_hd h[b,t,hd] * Wo[hd] + bo.  h f16 rows, fully dense reads.
// ---------------------------------------------------------------------------
__global__ __launch_bounds__(256) void proj_kernel(
    const ushort* __restrict__ hbuf, const float* __restrict__ Wo,
    const float* __restrict__ bo, float* __restrict__ out, int t0, int TCc) {

    const int lane = threadIdx.x & 63;
    const int wid  = blockIdx.x * 4 + (threadIdx.x >> 6);
    const int nw   = gridDim.x * 4;
    const int rows = B_ * TCc;

    float4 w = *(const float4*)(Wo + lane * 4);
    const float bov = bo[0];

    for (int r = wid; r < rows; r += nw) {
        const ushort* hp = hbuf + (size_t)r * H_ + lane * 4;
        ushort4 u = *(const ushort4*)hp;
        float p = h2f(u.x) * w.x + h2f(u.y) * w.y + h2f(u.z) * w.z + h2f(u.w) * w.w;
#pragma unroll
        for (int m = 1; m < 64; m <<= 1) p += __shfl_xor(p, m, 64);
        if (lane == 0) {
            int b  = r / TCc;
            int tl = r - b * TCc;
            out[(size_t)b * T_ + t0 + tl] = p + bov;
        }
    }
}

// ---------------------------------------------------------------------------
extern "C" void kernel_launch(void* const* d_in, const int* in_sizes, int n_in,
                              void* d_out, int out_size, void* d_ws, size_t ws_size,
                              hipStream_t stream) {
    const float* x   = (const float*)d_in[0];
    const float* Wih = (const float*)d_in[1];
    const float* Whh = (const float*)d_in[2];
    const float* bih = (const float*)d_in[3];
    const float* bhh = (const float*)d_in[4];
    const float* Wo  = (const float*)d_in[5];
    const float* bo  = (const float*)d_in[6];
    float* out = (float*)d_out;

    char* ws = (char*)d_ws;
    ushort* af    = (ushort*)ws;                              // 512 KB A-frags
    float*  state = (float*)(ws + 512 * 1024);                // 128 KB
    char*   dyn   = ws + 640 * 1024;                          // gx2 + hbuf chunks

    size_t avail = (ws_size > 640 * 1024) ? ws_size - 640 * 1024 : 0;
    // per (b,t): gx2 row 2048 B + hbuf row 512 B
    long long tcmax = (long long)(avail / ((size_t)B_ * (G4_ + H_) * 2));
    // Cap chunks at 512 steps so gx2 (64MB) + hbuf (16MB) stay L3-resident.
    int TC = (tcmax > 512) ? 512 : (int)tcmax;
    TC &= ~63;               // multiple of 64
    if (TC < 64) TC = 64;    // minimum viable chunk

    repack_kernel<<<1024, 256, 0, stream>>>(Whh, af);

    for (int t0 = 0; t0 < T_; t0 += TC) {
        int TCc = (T_ - t0 < TC) ? (T_ - t0) : TC;
        ushort* gxb  = (ushort*)dyn;
        ushort* hbuf = (ushort*)(dyn + (size_t)B_ * TCc * G4_ * 2);
        dim3 g1((B_ * TCc) / 32, 4);
        gx_kernel<<<g1, 256, 0, stream>>>(x, Wih, bih, bhh, gxb, t0, TCc);
        lstm_kernel<<<B_, 512, 0, stream>>>(af, gxb, hbuf, state, TCc, t0 == 0 ? 1 : 0);
        proj_kernel<<<256, 256, 0, stream>>>(hbuf, Wo, bo, out, t0, TCc);
    }
    (void)in_sizes; (void)n_in; (void)out_size;
}